// Round 3
// baseline (398.636 us; speedup 1.0000x reference)
//
#include <hip/hip_runtime.h>

#define HH 1024
#define WW 1024
#define NBATCH 32
#define ROWS 16
#define NBINS 256
#define NWAVES 4

// searchsorted(bins, x, 'left') - 1 with bins[i] = i/256 (exact in fp32).
// t = x*256 is exact (power-of-2 scale). idx = floor(t), minus 1 if t is
// exactly integral (left-side semantics). x==0 -> -1 (dropped).
__device__ inline int bin_of(float x) {
    float t = x * 256.0f;
    int it = (int)t;               // trunc == floor for x >= 0
    if ((float)it == t) it -= 1;
    return it;
}

__device__ inline float wave_red(float v) {
    #pragma unroll
    for (int off = 32; off > 0; off >>= 1) v += __shfl_down(v, off);
    return v;
}

__global__ __launch_bounds__(256, 8) void fused_main(
    const float* __restrict__ E, const float* __restrict__ O,
    unsigned int* __restrict__ gHistE, unsigned int* __restrict__ gHistO,
    double* __restrict__ sums)
{
    const int bt = blockIdx.y;
    const int r0 = blockIdx.x * ROWS;
    const float* __restrict__ e = E + (size_t)bt * HH * WW;
    const float* __restrict__ o = O + (size_t)bt * HH * WW;

    // per-wave private histograms: no inter-wave atomic contention
    __shared__ unsigned int hE[NWAVES][NBINS];
    __shared__ unsigned int hO[NWAVES][NBINS];
    __shared__ float rbuf[NWAVES][5];

    const int tid = threadIdx.x;
    {
        unsigned int* p = &hE[0][0];
        #pragma unroll
        for (int i = 0; i < NWAVES; ++i) p[tid + i * 256] = 0u;
        unsigned int* q = &hO[0][0];
        #pragma unroll
        for (int i = 0; i < NWAVES; ++i) q[tid + i * 256] = 0u;
    }
    __syncthreads();

    const int lane = tid & 63;
    const int wv   = tid >> 6;
    const int c    = tid * 4;            // 256 threads cover 1024 cols, 4 each
    const bool edgeL    = (lane == 0);
    const bool edgeR    = (lane == 63);
    const bool hasRight = (c + 4 < WW);  // false only for the last quad

    float prvE[4], prvO[4], curE[4], curO[4];
    {
        const float4 a = *reinterpret_cast<const float4*>(e + (size_t)r0 * WW + c);
        curE[0]=a.x; curE[1]=a.y; curE[2]=a.z; curE[3]=a.w;
        const float4 b = *reinterpret_cast<const float4*>(o + (size_t)r0 * WW + c);
        curO[0]=b.x; curO[1]=b.y; curO[2]=b.z; curO[3]=b.w;
        if (r0 > 0) {
            const float4 p = *reinterpret_cast<const float4*>(e + (size_t)(r0-1) * WW + c);
            prvE[0]=p.x; prvE[1]=p.y; prvE[2]=p.z; prvE[3]=p.w;
            const float4 q = *reinterpret_cast<const float4*>(o + (size_t)(r0-1) * WW + c);
            prvO[0]=q.x; prvO[1]=q.y; prvO[2]=q.z; prvO[3]=q.w;
        } else {
            #pragma unroll
            for (int j = 0; j < 4; ++j) { prvE[j] = 0.f; prvO[j] = 0.f; }
        }
    }

    float accL1 = 0.f, accLapE = 0.f, accLapO = 0.f, accDx = 0.f, accDy = 0.f;

    for (int r = r0; r < r0 + ROWS; ++r) {
        const int rn = r + 1;
        float nxtE[4], nxtO[4];
        if (rn < HH) {
            const float4 a = *reinterpret_cast<const float4*>(e + (size_t)rn * WW + c);
            nxtE[0]=a.x; nxtE[1]=a.y; nxtE[2]=a.z; nxtE[3]=a.w;
            const float4 b = *reinterpret_cast<const float4*>(o + (size_t)rn * WW + c);
            nxtO[0]=b.x; nxtO[1]=b.y; nxtO[2]=b.z; nxtO[3]=b.w;
        } else {
            #pragma unroll
            for (int j = 0; j < 4; ++j) { nxtE[j] = 0.f; nxtO[j] = 0.f; }
        }

        // horizontal neighbors via intra-wave shuffles; wave-edge lanes fall
        // back to (cached) scalar loads; image edges -> zero padding
        float lE = __shfl_up(curE[3], 1);
        float rE = __shfl_down(curE[0], 1);
        float lO = __shfl_up(curO[3], 1);
        float rO = __shfl_down(curO[0], 1);
        if (edgeL) {
            lE = (c > 0) ? e[(size_t)r * WW + c - 1] : 0.f;
            lO = (c > 0) ? o[(size_t)r * WW + c - 1] : 0.f;
        }
        if (edgeR) {
            rE = hasRight ? e[(size_t)r * WW + c + 4] : 0.f;
            rO = hasRight ? o[(size_t)r * WW + c + 4] : 0.f;
        }

        #pragma unroll
        for (int j = 0; j < 4; ++j) {
            const float le = (j == 0) ? lE : curE[j-1];
            const float re = (j == 3) ? rE : curE[j+1];
            accLapE += fabsf(prvE[j] + nxtE[j] + le + re - 4.f * curE[j]);
            const float lo = (j == 0) ? lO : curO[j-1];
            const float ro = (j == 3) ? rO : curO[j+1];
            accLapO += fabsf(prvO[j] + nxtO[j] + lo + ro - 4.f * curO[j]);
            accL1 += fabsf(curE[j] - curO[j]);
            const int be = bin_of(curE[j]);
            if (be >= 0 && be < NBINS) atomicAdd(&hE[wv][be], 1u);
            const int bo = bin_of(curO[j]);
            if (bo >= 0 && bo < NBINS) atomicAdd(&hO[wv][bo], 1u);
        }

        if (rn < HH) {
            #pragma unroll
            for (int j = 0; j < 4; ++j) accDx += fabsf(nxtE[j] - curE[j]);
        }
        accDy += fabsf(curE[1]-curE[0]) + fabsf(curE[2]-curE[1]) + fabsf(curE[3]-curE[2]);
        if (hasRight) accDy += fabsf(rE - curE[3]);

        #pragma unroll
        for (int j = 0; j < 4; ++j) {
            prvE[j] = curE[j]; curE[j] = nxtE[j];
            prvO[j] = curO[j]; curO[j] = nxtO[j];
        }
    }

    // block-reduce the 5 scalars, one fp64 atomic each per block
    float acc[5] = {accL1, accLapE, accLapO, accDx, accDy};
    #pragma unroll
    for (int k = 0; k < 5; ++k) {
        const float w = wave_red(acc[k]);
        if (lane == 0) rbuf[wv][k] = w;
    }
    __syncthreads();
    if (tid == 0) {
        #pragma unroll
        for (int k = 0; k < 5; ++k) {
            const double tot = (double)rbuf[0][k] + rbuf[1][k] + rbuf[2][k] + rbuf[3][k];
            atomicAdd(&sums[k], tot);
        }
    }

    // flush per-block histograms (tid == bin index); sum the 4 wave copies
    const unsigned int se = hE[0][tid] + hE[1][tid] + hE[2][tid] + hE[3][tid];
    const unsigned int so = hO[0][tid] + hO[1][tid] + hO[2][tid] + hO[3][tid];
    atomicAdd(&gHistE[bt * NBINS + tid], se);
    atomicAdd(&gHistO[bt * NBINS + tid], so);
}

__global__ __launch_bounds__(256) void finalize(
    const unsigned int* __restrict__ gHistE, const unsigned int* __restrict__ gHistO,
    const double* __restrict__ sums, float* __restrict__ out)
{
    __shared__ double sred[8];
    const int tid  = threadIdx.x;
    const int lane = tid & 63;
    const int wv   = tid >> 6;

    double hacc = 0.0;
    for (int bt = 0; bt < NBATCH; ++bt) {
        const double ce = (double)gHistE[bt * NBINS + tid];
        const double co = (double)gHistO[bt * NBINS + tid];
        double te = ce, to = co;
        #pragma unroll
        for (int off = 32; off > 0; off >>= 1) {
            te += __shfl_down(te, off);
            to += __shfl_down(to, off);
        }
        if (lane == 0) { sred[wv] = te; sred[4 + wv] = to; }
        __syncthreads();
        te = sred[0] + sred[1] + sred[2] + sred[3];
        to = sred[4] + sred[5] + sred[6] + sred[7];
        __syncthreads();
        const double he = (ce + 1e-6) / (te + 1e-6);
        const double ho = (co + 1e-6) / (te + 1e-6 - te + to + 1e-6 - 1e-6);  // == (co+1e-6)/(to+1e-6)
        const double d  = he - ho;
        hacc += d * d;
    }
    #pragma unroll
    for (int off = 32; off > 0; off >>= 1) hacc += __shfl_down(hacc, off);
    if (lane == 0) sred[wv] = hacc;
    __syncthreads();

    if (tid == 0) {
        const double hsum  = sred[0] + sred[1] + sred[2] + sred[3];
        const double hist  = hsum / ((double)NBATCH * NBINS) / (double)NBINS;
        const double N     = (double)NBATCH * HH * WW;
        const double l1    = sums[0] / N;
        const double cE    = sums[1] / N;
        const double cO    = sums[2] / N;
        const double cont  = fabs(cE - cO) / (cO + 1e-6);
        const double dxm   = sums[3] / ((double)NBATCH * (HH - 1) * WW);
        const double dym   = sums[4] / ((double)NBATCH * HH * (WW - 1));
        out[0] = (float)(l1 + 0.1 * hist + 0.1 * cont + 0.01 * (dxm + dym));
    }
}

extern "C" void kernel_launch(void* const* d_in, const int* in_sizes, int n_in,
                              void* d_out, int out_size, void* d_ws, size_t ws_size,
                              hipStream_t stream)
{
    const float* E = (const float*)d_in[0];  // enhanced_y
    const float* O = (const float*)d_in[1];  // original_y
    float* out = (float*)d_out;

    unsigned int* gHistE = (unsigned int*)d_ws;
    unsigned int* gHistO = gHistE + NBATCH * NBINS;
    double* sums = (double*)((char*)d_ws + (size_t)2 * NBATCH * NBINS * sizeof(unsigned int));

    // ws is poisoned 0xAA before every timed call -> zero the parts we use
    hipMemsetAsync(d_ws, 0,
                   (size_t)2 * NBATCH * NBINS * sizeof(unsigned int) + 8 * sizeof(double),
                   stream);

    dim3 grid(HH / ROWS, NBATCH);
    fused_main<<<grid, 256, 0, stream>>>(E, O, gHistE, gHistO, sums);
    finalize<<<1, 256, 0, stream>>>(gHistE, gHistO, sums, out);
}

// Round 4
// 297.437 us; speedup vs baseline: 1.3402x; 1.3402x over previous
//
#include <hip/hip_runtime.h>

#define HH 1024
#define WW 1024
#define NBATCH 32
#define ROWS 32
#define NBINS 256
#define NSLOT 8

// searchsorted(bins, x, 'left') - 1 with bins[i] = i/256 (exact in fp32).
// t = x*256 is exact (power-of-2 scale). idx = floor(t), minus 1 if t is
// exactly integral (left-side semantics). x==0 -> -1 (dropped).
__device__ inline int bin_of(float x) {
    float t = x * 256.0f;
    int it = (int)t;               // trunc == floor for x >= 0
    if ((float)it == t) it -= 1;
    return it;
}

__device__ inline float wave_red_f(float v) {
    #pragma unroll
    for (int off = 32; off > 0; off >>= 1) v += __shfl_down(v, off);
    return v;
}

__global__ __launch_bounds__(256, 4) void fused_main(
    const float* __restrict__ E, const float* __restrict__ O,
    unsigned int* __restrict__ gHistE, unsigned int* __restrict__ gHistO,
    double* __restrict__ sums)
{
    const int bt = blockIdx.y;
    const int r0 = blockIdx.x * ROWS;
    const float* __restrict__ e = E + (size_t)bt * HH * WW;
    const float* __restrict__ o = O + (size_t)bt * HH * WW;

    // block-shared, 8-way slot-replicated histograms: atomics protect
    // cross-wave updates; slot = tid&7 cuts same-address RMW serialization 8x
    __shared__ unsigned int hE[NBINS * NSLOT];
    __shared__ unsigned int hO[NBINS * NSLOT];
    __shared__ float rbuf[4][5];

    const int tid = threadIdx.x;
    #pragma unroll
    for (int i = 0; i < (NBINS * NSLOT) / 256; ++i) {
        hE[tid + i * 256] = 0u;
        hO[tid + i * 256] = 0u;
    }
    __syncthreads();

    const int lane = tid & 63;
    const int wv   = tid >> 6;
    const int slot = tid & (NSLOT - 1);
    const int c    = tid * 4;            // 256 threads cover 1024 cols, 4 each
    const bool edgeL    = (lane == 0);
    const bool edgeR    = (lane == 63);
    const bool hasRight = (c + 4 < WW);  // false only for the last quad

    auto loadrow = [&](const float* __restrict__ p, int r, float v[4]) {
        const float4 a = *reinterpret_cast<const float4*>(p + (size_t)r * WW + c);
        v[0] = a.x; v[1] = a.y; v[2] = a.z; v[3] = a.w;
    };

    // ---- software pipeline: rows r-1..r+1 resident, row r+3 in flight ----
    float prvE[4] = {0,0,0,0}, prvO[4] = {0,0,0,0};
    float curE[4], curO[4], nxtE[4], nxtO[4], p1E[4], p1O[4];
    if (r0 > 0) { loadrow(e, r0 - 1, prvE); loadrow(o, r0 - 1, prvO); }
    loadrow(e, r0,     curE); loadrow(o, r0,     curO);
    loadrow(e, r0 + 1, nxtE); loadrow(o, r0 + 1, nxtO);   // r0+1 <= 993 < HH always
    loadrow(e, r0 + 2, p1E);  loadrow(o, r0 + 2, p1O);    // r0+2 <= 994 < HH always

    // edge-lane horizontal neighbors for row r0 (pipelined 1 row ahead below)
    float lEc = 0.f, rEc = 0.f, lOc = 0.f, rOc = 0.f;
    if (edgeL && c > 0)    { lEc = e[(size_t)r0 * WW + c - 1]; lOc = o[(size_t)r0 * WW + c - 1]; }
    if (edgeR && hasRight) { rEc = e[(size_t)r0 * WW + c + 4]; rOc = o[(size_t)r0 * WW + c + 4]; }

    float accL1 = 0.f, accLapE = 0.f, accLapO = 0.f, accDx = 0.f, accDy = 0.f;

    for (int k = 0; k < ROWS; ++k) {
        const int r = r0 + k;

        // 2-deep row prefetch: row r+3 (needed rows cap at r0+ROWS)
        float p2E[4], p2O[4];
        if (k + 3 <= ROWS && r + 3 < HH) {
            loadrow(e, r + 3, p2E); loadrow(o, r + 3, p2O);
        } else {
            #pragma unroll
            for (int j = 0; j < 4; ++j) { p2E[j] = 0.f; p2O[j] = 0.f; }
        }

        // 1-deep edge prefetch: row r+1's horizontal neighbors
        float lEn = 0.f, rEn = 0.f, lOn = 0.f, rOn = 0.f;
        if (k + 1 < ROWS) {
            const int rn = r + 1;
            if (edgeL && c > 0)    { lEn = e[(size_t)rn * WW + c - 1]; lOn = o[(size_t)rn * WW + c - 1]; }
            if (edgeR && hasRight) { rEn = e[(size_t)rn * WW + c + 4]; rOn = o[(size_t)rn * WW + c + 4]; }
        }

        // horizontal neighbors via intra-wave shuffles (cur is >=2 iters old)
        float lE = __shfl_up(curE[3], 1);
        float rE = __shfl_down(curE[0], 1);
        float lO = __shfl_up(curO[3], 1);
        float rO = __shfl_down(curO[0], 1);
        if (edgeL) { lE = lEc; lO = lOc; }   // c==0 -> 0 (zero pad)
        if (edgeR) { rE = rEc; rO = rOc; }   // no right -> 0

        #pragma unroll
        for (int j = 0; j < 4; ++j) {
            const float le = (j == 0) ? lE : curE[j-1];
            const float re = (j == 3) ? rE : curE[j+1];
            accLapE += fabsf(prvE[j] + nxtE[j] + le + re - 4.f * curE[j]);
            const float lo = (j == 0) ? lO : curO[j-1];
            const float ro = (j == 3) ? rO : curO[j+1];
            accLapO += fabsf(prvO[j] + nxtO[j] + lo + ro - 4.f * curO[j]);
            accL1 += fabsf(curE[j] - curO[j]);
            const int be = bin_of(curE[j]);
            if (be >= 0 && be < NBINS) atomicAdd(&hE[be * NSLOT + slot], 1u);
            const int bo = bin_of(curO[j]);
            if (bo >= 0 && bo < NBINS) atomicAdd(&hO[bo * NSLOT + slot], 1u);
        }

        if (r + 1 < HH) {
            #pragma unroll
            for (int j = 0; j < 4; ++j) accDx += fabsf(nxtE[j] - curE[j]);
        }
        accDy += fabsf(curE[1]-curE[0]) + fabsf(curE[2]-curE[1]) + fabsf(curE[3]-curE[2]);
        if (hasRight) accDy += fabsf(rE - curE[3]);

        // rotate pipeline
        #pragma unroll
        for (int j = 0; j < 4; ++j) {
            prvE[j] = curE[j]; curE[j] = nxtE[j]; nxtE[j] = p1E[j]; p1E[j] = p2E[j];
            prvO[j] = curO[j]; curO[j] = nxtO[j]; nxtO[j] = p1O[j]; p1O[j] = p2O[j];
        }
        lEc = lEn; rEc = rEn; lOc = lOn; rOc = rOn;
    }

    // block-reduce the 5 scalars; per-batch f64 atomics (32 blocks/address)
    float acc[5] = {accL1, accLapE, accLapO, accDx, accDy};
    #pragma unroll
    for (int kk = 0; kk < 5; ++kk) {
        const float w = wave_red_f(acc[kk]);
        if (lane == 0) rbuf[wv][kk] = w;
    }
    __syncthreads();
    if (tid == 0) {
        #pragma unroll
        for (int kk = 0; kk < 5; ++kk) {
            const double tot = (double)rbuf[0][kk] + rbuf[1][kk] + rbuf[2][kk] + rbuf[3][kk];
            atomicAdd(&sums[bt * 5 + kk], tot);
        }
    }

    // flush histograms: thread tid owns bin tid, folds its 8 slots
    unsigned int se = 0u, so = 0u;
    #pragma unroll
    for (int s = 0; s < NSLOT; ++s) {
        se += hE[tid * NSLOT + s];
        so += hO[tid * NSLOT + s];
    }
    atomicAdd(&gHistE[bt * NBINS + tid], se);
    atomicAdd(&gHistO[bt * NBINS + tid], so);
}

__global__ __launch_bounds__(256) void finalize(
    const unsigned int* __restrict__ gHistE, const unsigned int* __restrict__ gHistO,
    const double* __restrict__ sums, float* __restrict__ out)
{
    __shared__ double teL[NBATCH], toL[NBATCH];
    __shared__ double red[4];
    const int tid  = threadIdx.x;
    const int lane = tid & 63;
    const int wv   = tid >> 6;

    // phase 1: per-batch totals, one wave per 8 batches, no block syncs
    #pragma unroll
    for (int i = 0; i < NBATCH / 4; ++i) {
        const int bt = wv * (NBATCH / 4) + i;
        const uint4 a = *reinterpret_cast<const uint4*>(&gHistE[bt * NBINS + lane * 4]);
        const uint4 b = *reinterpret_cast<const uint4*>(&gHistO[bt * NBINS + lane * 4]);
        unsigned int te = a.x + a.y + a.z + a.w;
        unsigned int to = b.x + b.y + b.z + b.w;
        #pragma unroll
        for (int off = 32; off > 0; off >>= 1) {
            te += __shfl_down(te, off);
            to += __shfl_down(to, off);
        }
        if (lane == 0) { teL[bt] = (double)te; toL[bt] = (double)to; }
    }
    __syncthreads();

    // phase 2: thread owns bin=tid across all batches (loads are L2-hot)
    double hacc = 0.0;
    for (int bt = 0; bt < NBATCH; ++bt) {
        const double ce = (double)gHistE[bt * NBINS + tid];
        const double co = (double)gHistO[bt * NBINS + tid];
        const double he = (ce + 1e-6) / (teL[bt] + 1e-6);
        const double ho = (co + 1e-6) / (toL[bt] + 1e-6);
        const double d  = he - ho;
        hacc += d * d;
    }
    #pragma unroll
    for (int off = 32; off > 0; off >>= 1) hacc += __shfl_down(hacc, off);
    if (lane == 0) red[wv] = hacc;

    // wave 0 reduces the per-batch scalar sums meanwhile
    double s0 = 0, s1 = 0, s2 = 0, s3 = 0, s4 = 0;
    if (wv == 0) {
        if (lane < NBATCH) {
            s0 = sums[lane * 5 + 0]; s1 = sums[lane * 5 + 1]; s2 = sums[lane * 5 + 2];
            s3 = sums[lane * 5 + 3]; s4 = sums[lane * 5 + 4];
        }
        #pragma unroll
        for (int off = 32; off > 0; off >>= 1) {
            s0 += __shfl_down(s0, off); s1 += __shfl_down(s1, off);
            s2 += __shfl_down(s2, off); s3 += __shfl_down(s3, off);
            s4 += __shfl_down(s4, off);
        }
    }
    __syncthreads();

    if (tid == 0) {
        const double hsum = red[0] + red[1] + red[2] + red[3];
        const double hist = hsum / ((double)NBATCH * NBINS) / (double)NBINS;
        const double N    = (double)NBATCH * HH * WW;
        const double l1   = s0 / N;
        const double cE   = s1 / N;
        const double cO   = s2 / N;
        const double cont = fabs(cE - cO) / (cO + 1e-6);
        const double dxm  = s3 / ((double)NBATCH * (HH - 1) * WW);
        const double dym  = s4 / ((double)NBATCH * HH * (WW - 1));
        out[0] = (float)(l1 + 0.1 * hist + 0.1 * cont + 0.01 * (dxm + dym));
    }
}

extern "C" void kernel_launch(void* const* d_in, const int* in_sizes, int n_in,
                              void* d_out, int out_size, void* d_ws, size_t ws_size,
                              hipStream_t stream)
{
    const float* E = (const float*)d_in[0];  // enhanced_y
    const float* O = (const float*)d_in[1];  // original_y
    float* out = (float*)d_out;

    unsigned int* gHistE = (unsigned int*)d_ws;
    unsigned int* gHistO = gHistE + NBATCH * NBINS;
    double* sums = (double*)((char*)d_ws + (size_t)2 * NBATCH * NBINS * sizeof(unsigned int));

    // ws is poisoned 0xAA before every timed call -> zero the parts we use
    hipMemsetAsync(d_ws, 0,
                   (size_t)2 * NBATCH * NBINS * sizeof(unsigned int)
                   + (size_t)NBATCH * 5 * sizeof(double),
                   stream);

    dim3 grid(HH / ROWS, NBATCH);
    fused_main<<<grid, 256, 0, stream>>>(E, O, gHistE, gHistO, sums);
    finalize<<<1, 256, 0, stream>>>(gHistE, gHistO, sums, out);
}